// Round 5
// baseline (339.975 us; speedup 1.0000x reference)
//
#include <hip/hip_runtime.h>

// Problem constants (fixed by reference)
#define TT 2048
#define BB 16384
#define NSTEP 18431      // TT + BB - 1
#define HOR 24
#define MM 24            // seasonality period

// Chunked-speculation parameters
#define PCH 128          // parallel chunks (2 waves, lane = chunk)
#define CLEN 144         // steps per chunk; PCH*CLEN = 18432 = NSTEP+1; multiple of 24
#define WARM 1248        // warm-up steps = 52*24; slow-mode residual ~0.919^52 (absmax 4096, 3x margin)

#define NTOT (PCH * CLEN)   // 18432

// Workspace layout (floats)
#define SEG 20480        // per-array segment (multiple of 4; > NSTEP+MM)
// ws+0        : ts[SEG]    input series (padded with 1.0f at index NSTEP)
// ws+SEG      : xn[SEG]    normalized outputs (lambda-invariant)
// ws+2*SEG    : larr[SEG]  level per step (chunk-frame; corrected on the fly in fill)
// ws+3*SEG    : Sarr[SEG]  S_t (index t; S_{t+24} written at step t; [0,24) unused)
// ws+4*SEG    : lamg[PCH]  per-chunk lambda
// ws+4*SEG+PCH: ilamg[PCH] per-chunk 1/lambda

#define FILLA_BLOCKS 32768            // (BB*TT/4)/256
#define FILLB_BLOCKS 1536             // (BB*HOR)/256

typedef float f4v __attribute__((ext_vector_type(4)));

__device__ __forceinline__ float frcp(float x) {        // ~0.5 ulp
    float r = __builtin_amdgcn_rcpf(x);
    return r * fmaf(-x, r, 2.0f);
}
__device__ __forceinline__ float frcp_fast(float x) {   // raw v_rcp_f32, ~1 ulp
    return __builtin_amdgcn_rcpf(x);
}

__global__ void __launch_bounds__(PCH, 1) scan_kernel(const float* __restrict__ x,
                                                      const float* __restrict__ alpha,
                                                      const float* __restrict__ gamma,
                                                      const float* __restrict__ init_seas,
                                                      const float* __restrict__ level,
                                                      float* __restrict__ ws) {
    const int i = threadIdx.x;                 // chunk id, one lane per chunk
    float* ts    = ws;
    float* xn    = ws + SEG;
    float* larr  = ws + 2 * SEG;
    float* Sarr  = ws + 3 * SEG;
    float* lamg  = ws + 4 * SEG;
    float* ilamg = ws + 4 * SEG + PCH;

    __shared__ float sm_warm[PCH], sm_end[PCH], sm_ll[PCH];

    // ---- phase 0: gather the series (fused former prep_kernel) ----
    // ts[k] = x[0,k,0] for k<TT ; x[k-(TT-1), TT-1, 0] for k<NSTEP ; 1.0 pad at k=NSTEP
#pragma unroll 16
    for (int k = i; k < NTOT; k += PCH) {
        float v;
        if (k < TT)          v = x[k];
        else if (k < NSTEP)  v = x[(size_t)(k - (TT - 1)) * TT + (TT - 1)];
        else                 v = 1.0f;
        ts[k] = v;
    }

    const float a  = alpha[0];
    const float g  = gamma[0];
    const float oa = 1.0f - a;
    const float og = 1.0f - g;

    float l = level[0];
    float s[MM];
#pragma unroll
    for (int j = 0; j < MM; ++j) s[j] = init_seas[j];   // guess; chunks with cstart<=WARM are exact

    __syncthreads();   // gather visible to all lanes (vmcnt drained by barrier semantics)

    const int cstart = i * CLEN;
    int t = cstart - WARM;
    if (t < 0) t = 0;

    // ---- warm-up (no stores): contracts all non-neutral modes (slowest ~0.919/cycle) ----
    for (; t < cstart; t += MM) {
        float yv[MM];
#pragma unroll
        for (int q = 0; q < MM / 4; ++q) {
            const float4 v = *(const float4*)(ts + t + 4 * q);
            yv[4*q+0] = v.x; yv[4*q+1] = v.y; yv[4*q+2] = v.z; yv[4*q+3] = v.w;
        }
#pragma unroll
        for (int j = 0; j < MM; ++j) {
            const float y  = yv[j];
            const float u  = y * frcp_fast(s[j]);        // y / S_t (raw rcp: error contracts)
            l = fmaf(oa, l, a * u);                      // level update (the only serial chain)
            s[j] = fmaf(og, s[j], g * y * frcp_fast(l)); // S_{t+24}
        }
    }
    // Geometric-mean handoff signature: sum_j log2 s_j at time cstart.
    // Non-neutral eigenmodes have s-part ~ omega^j with sum_j omega^j = 0 ->
    // first-order contamination cancels; only the neutral (lambda) offset survives.
    {
        float m = 0.0f;
#pragma unroll
        for (int j = 0; j < MM; ++j) m += __log2f(s[j]);
        sm_warm[i] = m;
    }

    // ---- main chunk (store xn, l, S) ----
    const int cend = cstart + CLEN;
    for (; t < cend; t += MM) {
        float yv[MM], xv[MM], lv[MM], sv[MM];
#pragma unroll
        for (int q = 0; q < MM / 4; ++q) {
            const float4 v = *(const float4*)(ts + t + 4 * q);
            yv[4*q+0] = v.x; yv[4*q+1] = v.y; yv[4*q+2] = v.z; yv[4*q+3] = v.w;
        }
#pragma unroll
        for (int j = 0; j < MM; ++j) {
            const float y  = yv[j];
            const float u  = y * frcp(s[j]);
            l = fmaf(oa, l, a * u);
            const float rl = frcp(l);
            s[j] = fmaf(og, s[j], g * y * rl);
            xv[j] = u * rl;                           // y / (S_t * l_t)  (lambda-invariant)
            lv[j] = l;
            sv[j] = s[j];
        }
#pragma unroll
        for (int q = 0; q < MM / 4; ++q) {
            *(float4*)(xn   + t + 4 * q)      = make_float4(xv[4*q], xv[4*q+1], xv[4*q+2], xv[4*q+3]);
            *(float4*)(larr + t + 4 * q)      = make_float4(lv[4*q], lv[4*q+1], lv[4*q+2], lv[4*q+3]);
            *(float4*)(Sarr + MM + t + 4 * q) = make_float4(sv[4*q], sv[4*q+1], sv[4*q+2], sv[4*q+3]);
        }
    }
    // signature at time cend (same time point as chunk i+1's sm_warm)
    {
        float m = 0.0f;
#pragma unroll
        for (int j = 0; j < MM; ++j) m += __log2f(s[j]);
        sm_end[i] = m;
    }
    __syncthreads();

    // ---- lambda chain (Hillis-Steele prefix over log-lambda increments) ----
    // l~ = lam_c * l_true ; s~ = s_true / lam_c
    // log2(lam_c/lam_{c-1}) = (mend[c-1] - mwarm[c]) / 24
    float d = (i == 0) ? 0.0f : (sm_end[i - 1] - sm_warm[i]) * (1.0f / 24.0f);
    sm_ll[i] = d;
    __syncthreads();
#pragma unroll
    for (int off = 1; off < PCH; off <<= 1) {
        float add = (i >= off) ? sm_ll[i - off] : 0.0f;
        __syncthreads();
        sm_ll[i] += add;
        __syncthreads();
    }
    const float ll = sm_ll[i];
    lamg[i]  = exp2f(ll);
    ilamg[i] = exp2f(-ll);
}

__global__ void __launch_bounds__(256) fill_kernel(const float* __restrict__ ws,
                                                   float* __restrict__ out) {
    const float* xn    = ws + SEG;
    const float* larr  = ws + 2 * SEG;
    const float* Sarr  = ws + 3 * SEG;
    const float* lamg  = ws + 4 * SEG;
    const float* ilamg = ws + 4 * SEG + PCH;
    const int bid = blockIdx.x;

    if (bid < FILLA_BLOCKS) {
        // x_out[b, t] = xn[b + t] ; one float4 of t per thread; streaming nt store
        const int q  = bid * 256 + threadIdx.x;      // [0, BB*TT/4)
        const int b  = q >> 9;                       // / (TT/4)
        const int t0 = (q & 511) << 2;
        const int src = b + t0;
        f4v v;
        v.x = xn[src]; v.y = xn[src + 1]; v.z = xn[src + 2]; v.w = xn[src + 3];
        __builtin_nontemporal_store(v, (f4v*)(out + ((size_t)b * TT + t0)));
    } else {
        // denorm[b, h, 0] = l[2047+b]/lam ; denorm[b, h, 1] = S[2048+b+h]*lam
        __shared__ float slam[PCH], silam[PCH];
        if (threadIdx.x < PCH) {
            slam[threadIdx.x]  = lamg[threadIdx.x];
            silam[threadIdx.x] = ilamg[threadIdx.x];
        }
        __syncthreads();
        const int r = (bid - FILLA_BLOCKS) * 256 + threadIdx.x;  // [0, BB*HOR)
        const int b = r / HOR;
        const int h = r - b * HOR;
        const int tl  = (TT - 1) + b;                // larr time index
        const int tsx = TT + b + h;                  // Sarr array index (written at step tsx-MM)
        const float lev = larr[tl]  * silam[tl / CLEN];
        const float se  = Sarr[tsx] * slam[(tsx - MM) / CLEN];
        *(float2*)(out + (size_t)BB * TT + 2 * (size_t)r) = make_float2(lev, se);
    }
}

extern "C" void kernel_launch(void* const* d_in, const int* in_sizes, int n_in,
                              void* d_out, int out_size, void* d_ws, size_t ws_size,
                              hipStream_t stream) {
    const float* x     = (const float*)d_in[0];
    const float* alpha = (const float*)d_in[1];
    const float* gamma = (const float*)d_in[2];
    const float* iseas = (const float*)d_in[3];
    const float* level = (const float*)d_in[4];
    float* ws  = (float*)d_ws;
    float* out = (float*)d_out;

    scan_kernel<<<1, PCH, 0, stream>>>(x, alpha, gamma, iseas, level, ws);
    fill_kernel<<<FILLA_BLOCKS + FILLB_BLOCKS, 256, 0, stream>>>(ws, out);
}

// Round 6
// 243.712 us; speedup vs baseline: 1.3950x; 1.3950x over previous
//
#include <hip/hip_runtime.h>

// Problem constants (fixed by reference)
#define TT 2048
#define BB 16384
#define NSTEP 18431      // TT + BB - 1
#define HOR 24
#define MM 24            // seasonality period

// Chunked-speculation parameters
#define PCH 128          // parallel chunks (2 waves, lane = chunk)
#define CLEN 144         // steps per chunk; PCH*CLEN = 18432 = NSTEP+1; multiple of 24
#define WARM 1248        // warm-up steps = 52*24; slow-mode residual ~0.919^52 (absmax 4096, 3x margin)

#define NTOT (PCH * CLEN)   // 18432

// Workspace layout (floats)
#define SEG 20480        // per-array segment (multiple of 4; > NTOT+MM)
// ws+0        : ts[SEG]    input series (padded with 1.0f from NSTEP to SEG)
// ws+SEG      : xn[SEG]    normalized outputs (lambda-invariant)
// ws+2*SEG    : larr[SEG]  level per step (chunk-frame; corrected on the fly in fill)
// ws+3*SEG    : Sarr[SEG]  S_t (index t; S_{t+24} written at step t; [0,24) unused)
// ws+4*SEG    : lamg[PCH]  per-chunk lambda
// ws+4*SEG+PCH: ilamg[PCH] per-chunk 1/lambda

#define FILLA_BLOCKS 32768            // (BB*TT/4)/256
#define FILLB_BLOCKS 1536             // (BB*HOR)/256

typedef float f4v __attribute__((ext_vector_type(4)));

__device__ __forceinline__ float frcp_fast(float x) {   // raw v_rcp_f32, ~1 ulp
    return __builtin_amdgcn_rcpf(x);
}

// Wide-grid gather: one thread per ts element. 18432-way MLP vs the fused
// single-block version's ~32 outstanding loads (R5: 135 us, FETCH=1MB — the
// scattered x[b,2047] reads serialize on HBM latency without grid parallelism).
__global__ void __launch_bounds__(256) prep_kernel(const float* __restrict__ x,
                                                   float* __restrict__ ws) {
    int tid = blockIdx.x * blockDim.x + threadIdx.x;
    float* ts = ws;
    if (tid < SEG) {
        float v;
        if (tid < TT)          v = x[tid];                                      // x[0, t, 0]
        else if (tid < NSTEP)  v = x[(size_t)(tid - (TT - 1)) * TT + (TT - 1)]; // x[b, T-1, 0]
        else                   v = 1.0f;                                        // pad (covers prefetch)
        ts[tid] = v;
    }
}

__global__ void __launch_bounds__(PCH, 1) scan_kernel(const float* __restrict__ alpha,
                                                      const float* __restrict__ gamma,
                                                      const float* __restrict__ init_seas,
                                                      const float* __restrict__ level,
                                                      float* __restrict__ ws) {
    const int i = threadIdx.x;                 // chunk id, one lane per chunk
    const float* ts = ws;
    float* xn    = ws + SEG;
    float* larr  = ws + 2 * SEG;
    float* Sarr  = ws + 3 * SEG;
    float* lamg  = ws + 4 * SEG;
    float* ilamg = ws + 4 * SEG + PCH;

    __shared__ float sm_warm[PCH], sm_end[PCH], sm_ll[PCH];

    const float a  = alpha[0];
    const float g  = gamma[0];
    const float oa = 1.0f - a;
    const float og = 1.0f - g;

    float l = level[0];
    float s[MM];
#pragma unroll
    for (int j = 0; j < MM; ++j) s[j] = init_seas[j];   // guess; chunks with cstart<=WARM are exact

    const int cstart = i * CLEN;
    const int cend   = cstart + CLEN;
    int t = cstart - WARM;
    if (t < 0) t = 0;

    // Register prefetch pipeline: group g+1's 6 float4 loads issue before group
    // g's 24-step body, so the ~200cyc L2 latency is covered by ~500cyc compute.
    float4 p0 = *(const float4*)(ts + t);
    float4 p1 = *(const float4*)(ts + t + 4);
    float4 p2 = *(const float4*)(ts + t + 8);
    float4 p3 = *(const float4*)(ts + t + 12);
    float4 p4 = *(const float4*)(ts + t + 16);
    float4 p5 = *(const float4*)(ts + t + 20);

    // ---- warm-up (no stores): contracts all non-neutral modes (slowest ~0.919/cycle) ----
    for (; t < cstart; t += MM) {
        float yv[MM];
        yv[0]=p0.x; yv[1]=p0.y; yv[2]=p0.z; yv[3]=p0.w;
        yv[4]=p1.x; yv[5]=p1.y; yv[6]=p1.z; yv[7]=p1.w;
        yv[8]=p2.x; yv[9]=p2.y; yv[10]=p2.z; yv[11]=p2.w;
        yv[12]=p3.x; yv[13]=p3.y; yv[14]=p3.z; yv[15]=p3.w;
        yv[16]=p4.x; yv[17]=p4.y; yv[18]=p4.z; yv[19]=p4.w;
        yv[20]=p5.x; yv[21]=p5.y; yv[22]=p5.z; yv[23]=p5.w;
        p0 = *(const float4*)(ts + t + MM);
        p1 = *(const float4*)(ts + t + MM + 4);
        p2 = *(const float4*)(ts + t + MM + 8);
        p3 = *(const float4*)(ts + t + MM + 12);
        p4 = *(const float4*)(ts + t + MM + 16);
        p5 = *(const float4*)(ts + t + MM + 20);
#pragma unroll
        for (int j = 0; j < MM; ++j) {
            const float y  = yv[j];
            const float u  = y * frcp_fast(s[j]);        // y / S_t (raw rcp: error contracts)
            l = fmaf(oa, l, a * u);                      // level update (the only serial chain)
            s[j] = fmaf(og, s[j], g * y * frcp_fast(l)); // S_{t+24}
        }
    }
    // Geometric-mean handoff signature: sum_j log2 s_j at time cstart.
    // Non-neutral eigenmodes have s-part ~ omega^j with sum_j omega^j = 0 ->
    // first-order contamination cancels; only the neutral (lambda) offset survives.
    {
        float m = 0.0f;
#pragma unroll
        for (int j = 0; j < MM; ++j) m += __log2f(s[j]);
        sm_warm[i] = m;
    }

    // ---- main chunk (store xn, l, S) ----
    for (; t < cend; t += MM) {
        float yv[MM], xv[MM], lv[MM], sv[MM];
        yv[0]=p0.x; yv[1]=p0.y; yv[2]=p0.z; yv[3]=p0.w;
        yv[4]=p1.x; yv[5]=p1.y; yv[6]=p1.z; yv[7]=p1.w;
        yv[8]=p2.x; yv[9]=p2.y; yv[10]=p2.z; yv[11]=p2.w;
        yv[12]=p3.x; yv[13]=p3.y; yv[14]=p3.z; yv[15]=p3.w;
        yv[16]=p4.x; yv[17]=p4.y; yv[18]=p4.z; yv[19]=p4.w;
        yv[20]=p5.x; yv[21]=p5.y; yv[22]=p5.z; yv[23]=p5.w;
        // prefetch next group (last one reads ts[NTOT..NTOT+23] — padded, unused)
        p0 = *(const float4*)(ts + t + MM);
        p1 = *(const float4*)(ts + t + MM + 4);
        p2 = *(const float4*)(ts + t + MM + 8);
        p3 = *(const float4*)(ts + t + MM + 12);
        p4 = *(const float4*)(ts + t + MM + 16);
        p5 = *(const float4*)(ts + t + MM + 20);
#pragma unroll
        for (int j = 0; j < MM; ++j) {
            const float y  = yv[j];
            const float u  = y * frcp_fast(s[j]);
            l = fmaf(oa, l, a * u);
            const float rl = frcp_fast(l);
            s[j] = fmaf(og, s[j], g * y * rl);
            xv[j] = u * rl;                           // y / (S_t * l_t)  (lambda-invariant)
            lv[j] = l;
            sv[j] = s[j];
        }
#pragma unroll
        for (int q = 0; q < MM / 4; ++q) {
            *(float4*)(xn   + t + 4 * q)      = make_float4(xv[4*q], xv[4*q+1], xv[4*q+2], xv[4*q+3]);
            *(float4*)(larr + t + 4 * q)      = make_float4(lv[4*q], lv[4*q+1], lv[4*q+2], lv[4*q+3]);
            *(float4*)(Sarr + MM + t + 4 * q) = make_float4(sv[4*q], sv[4*q+1], sv[4*q+2], sv[4*q+3]);
        }
    }
    // signature at time cend (same time point as chunk i+1's sm_warm)
    {
        float m = 0.0f;
#pragma unroll
        for (int j = 0; j < MM; ++j) m += __log2f(s[j]);
        sm_end[i] = m;
    }
    __syncthreads();

    // ---- lambda chain (Hillis-Steele prefix over log-lambda increments) ----
    // l~ = lam_c * l_true ; s~ = s_true / lam_c
    // log2(lam_c/lam_{c-1}) = (mend[c-1] - mwarm[c]) / 24
    float d = (i == 0) ? 0.0f : (sm_end[i - 1] - sm_warm[i]) * (1.0f / 24.0f);
    sm_ll[i] = d;
    __syncthreads();
#pragma unroll
    for (int off = 1; off < PCH; off <<= 1) {
        float add = (i >= off) ? sm_ll[i - off] : 0.0f;
        __syncthreads();
        sm_ll[i] += add;
        __syncthreads();
    }
    const float ll = sm_ll[i];
    lamg[i]  = exp2f(ll);
    ilamg[i] = exp2f(-ll);
}

__global__ void __launch_bounds__(256) fill_kernel(const float* __restrict__ ws,
                                                   float* __restrict__ out) {
    const float* xn    = ws + SEG;
    const float* larr  = ws + 2 * SEG;
    const float* Sarr  = ws + 3 * SEG;
    const float* lamg  = ws + 4 * SEG;
    const float* ilamg = ws + 4 * SEG + PCH;
    const int bid = blockIdx.x;

    if (bid < FILLA_BLOCKS) {
        // x_out[b, t] = xn[b + t] ; one float4 of t per thread; streaming nt store
        const int q  = bid * 256 + threadIdx.x;      // [0, BB*TT/4)
        const int b  = q >> 9;                       // / (TT/4)
        const int t0 = (q & 511) << 2;
        const int src = b + t0;
        f4v v;
        v.x = xn[src]; v.y = xn[src + 1]; v.z = xn[src + 2]; v.w = xn[src + 3];
        __builtin_nontemporal_store(v, (f4v*)(out + ((size_t)b * TT + t0)));
    } else {
        // denorm[b, h, 0] = l[2047+b]/lam ; denorm[b, h, 1] = S[2048+b+h]*lam
        __shared__ float slam[PCH], silam[PCH];
        if (threadIdx.x < PCH) {
            slam[threadIdx.x]  = lamg[threadIdx.x];
            silam[threadIdx.x] = ilamg[threadIdx.x];
        }
        __syncthreads();
        const int r = (bid - FILLA_BLOCKS) * 256 + threadIdx.x;  // [0, BB*HOR)
        const int b = r / HOR;
        const int h = r - b * HOR;
        const int tl  = (TT - 1) + b;                // larr time index
        const int tsx = TT + b + h;                  // Sarr array index (written at step tsx-MM)
        const float lev = larr[tl]  * silam[tl / CLEN];
        const float se  = Sarr[tsx] * slam[(tsx - MM) / CLEN];
        *(float2*)(out + (size_t)BB * TT + 2 * (size_t)r) = make_float2(lev, se);
    }
}

extern "C" void kernel_launch(void* const* d_in, const int* in_sizes, int n_in,
                              void* d_out, int out_size, void* d_ws, size_t ws_size,
                              hipStream_t stream) {
    const float* x     = (const float*)d_in[0];
    const float* alpha = (const float*)d_in[1];
    const float* gamma = (const float*)d_in[2];
    const float* iseas = (const float*)d_in[3];
    const float* level = (const float*)d_in[4];
    float* ws  = (float*)d_ws;
    float* out = (float*)d_out;

    prep_kernel<<<SEG / 256, 256, 0, stream>>>(x, ws);
    scan_kernel<<<1, PCH, 0, stream>>>(alpha, gamma, iseas, level, ws);
    fill_kernel<<<FILLA_BLOCKS + FILLB_BLOCKS, 256, 0, stream>>>(ws, out);
}